// Round 5
// baseline (140.650 us; speedup 1.0000x reference)
//
#include <hip/hip_runtime.h>

typedef __attribute__((ext_vector_type(8))) short short8;
typedef __attribute__((ext_vector_type(4))) float float4v;

#define BATCH 16
#define CDIM 2048
#define LDIM 64
#define BSTRIDE (CDIM * LDIM) /* 131072 elems per batch */

__device__ __forceinline__ float bf2f(unsigned short u) {
    return __uint_as_float(((unsigned int)u) << 16);
}
__device__ __forceinline__ unsigned short f2bf(float f) {
    unsigned int x = __float_as_uint(f);
    x += 0x7fffu + ((x >> 16) & 1u); // RNE
    return (unsigned short)(x >> 16);
}
// Async global->LDS DMA: 16B/lane, lane i lands at lptr + i*16. lptr wave-uniform.
__device__ __forceinline__ void dma16(const void* g, void* l) {
    __builtin_amdgcn_global_load_lds(
        (const __attribute__((address_space(1))) void*)g,
        (__attribute__((address_space(3))) void*)l, 16, 0, 0);
}

// ---- Prepass (one launch, 3072 blocks x 256):
//  [0,1024)    zero out (32B/thread)
//  [1024,2048) q*0.125 -> swizzled bf16 (chunk j at j^(m&7) within 128B row)
//  [2048,2560) k (64i x 2048n) -> kT[b][n][i] bf16, chunk-swizzled
//  [2560,3072) v (2048n x 64j) -> vS[b][nb][j][nn] bf16, chunk-swizzled
__global__ __launch_bounds__(256) void prepass_kernel(
    const float* __restrict__ q, const float* __restrict__ k, const float* __restrict__ v,
    float* __restrict__ out, unsigned short* __restrict__ qb,
    unsigned short* __restrict__ kT, unsigned short* __restrict__ vS)
{
    __shared__ unsigned short T[64][68];
    const int bx = blockIdx.x;
    const int t = threadIdx.x;

    if (bx < 1024) {
        float4v z = (float4v){0.f, 0.f, 0.f, 0.f};
        float4v* o = (float4v*)out + (size_t)bx * 512 + t * 2;
        o[0] = z; o[1] = z;
    } else if (bx < 2048) {
        int i = (bx - 1024) * 256 + t; // one 16B out-chunk (8 bf16) per thread
        const float4v* src = (const float4v*)q + (size_t)i * 2;
        float4v x0 = src[0], x1 = src[1];
        unsigned int u0 = f2bf(x0[0] * 0.125f) | ((unsigned)f2bf(x0[1] * 0.125f) << 16);
        unsigned int u1 = f2bf(x0[2] * 0.125f) | ((unsigned)f2bf(x0[3] * 0.125f) << 16);
        unsigned int u2 = f2bf(x1[0] * 0.125f) | ((unsigned)f2bf(x1[1] * 0.125f) << 16);
        unsigned int u3 = f2bf(x1[2] * 0.125f) | ((unsigned)f2bf(x1[3] * 0.125f) << 16);
        int b = i >> 14, r = i & 16383, m = r >> 3, j = r & 7;
        *(uint4*)(qb + (size_t)b * BSTRIDE + m * 64 + (j ^ (m & 7)) * 8) =
            make_uint4(u0, u1, u2, u3);
    } else if (bx < 2560) { // k-transpose: tile = all 64 i x 64 n
        int idx = bx - 2048, b = idx >> 5, n0 = (idx & 31) * 64;
        const float* src = k + (size_t)b * BSTRIDE + (size_t)(t >> 2) * 2048 + n0 + (t & 3) * 16;
        // load 16 fp32 (4 float4) of row i=t>>2, cols (t&3)*16..+15 -> LDS[i][n]
#pragma unroll
        for (int kk = 0; kk < 4; kk++) {
            float4v x = *(const float4v*)(src + kk * 4);
#pragma unroll
            for (int e = 0; e < 4; e++)
                T[t >> 2][(t & 3) * 16 + kk * 4 + e] = f2bf(x[e]);
        }
        __syncthreads();
        unsigned short* dst = kT + (size_t)b * BSTRIDE;
        int n = t & 63;
#pragma unroll
        for (int jj = 0; jj < 2; jj++) {
            int j = (t >> 6) * 2 + jj;
            ushort4 g0, g1;
#pragma unroll
            for (int e = 0; e < 4; e++) { g0[e] = T[j * 8 + e][n]; g1[e] = T[j * 8 + 4 + e][n]; }
            *(uint4*)(dst + (size_t)(n0 + n) * 64 + (j ^ (n & 7)) * 8) =
                make_uint4(g0.x | ((unsigned)g0.y << 16), g0.z | ((unsigned)g0.w << 16),
                           g1.x | ((unsigned)g1.y << 16), g1.z | ((unsigned)g1.w << 16));
        }
    } else { // v-transpose: tile = 64 n x 64 j
        int idx = bx - 2560, b = idx >> 5, n0 = (idx & 31) * 64;
        const float* src = v + (size_t)b * BSTRIDE + (size_t)(t >> 2) * 64 + n0 * 0 + (t & 3) * 16;
        src += (size_t)n0 * 64; // row n = n0 + (t>>2)
#pragma unroll
        for (int kk = 0; kk < 4; kk++) {
            float4v x = *(const float4v*)(src + kk * 4);
#pragma unroll
            for (int e = 0; e < 4; e++)
                T[t >> 2][(t & 3) * 16 + kk * 4 + e] = f2bf(x[e]); // T[n][j]
        }
        __syncthreads();
        unsigned short* dst = vS + (size_t)b * BSTRIDE;
        int j = t & 63, qc = t >> 6;
#pragma unroll
        for (int nb = 0; nb < 2; nb++) {
            ushort4 g0, g1;
#pragma unroll
            for (int e = 0; e < 4; e++) {
                g0[e] = T[nb * 32 + qc * 8 + e][j];
                g1[e] = T[nb * 32 + qc * 8 + 4 + e][j];
            }
            *(uint4*)(dst + (size_t)(n0 / 32 + nb) * 2048 + j * 32 + (qc ^ (j & 3)) * 8) =
                make_uint4(g0.x | ((unsigned)g0.y << 16), g0.z | ((unsigned)g0.w << 16),
                           g1.x | ((unsigned)g1.y << 16), g1.z | ((unsigned)g1.w << 16));
        }
    }
}

// ---- dinv: frag-direct Dt[T][w][ms][nt][lane] (uint2 of 4 bf16 1/D). Pipelined over batches.
// Grid 512 = 16 mt x 32 ng; block 256 = 4 waves; 2 blocks/CU.
__global__ __launch_bounds__(256, 2) void dinv_kernel(
    const unsigned short* __restrict__ qb, const unsigned short* __restrict__ kT,
    unsigned short* __restrict__ Dt)
{
    __shared__ unsigned short Sq[2][8192]; // 2 x 16KB : 128m x 64i
    __shared__ unsigned short Sk[2][4096]; // 2 x 8KB  : 64n x 64i
    const int tid = threadIdx.x, w = tid >> 6, lane = tid & 63;
    const int c = lane & 15, q = lane >> 4;
    const int mt = blockIdx.x & 15, ng = blockIdx.x >> 4;
    const int m0 = mt * 128, n0 = ng * 64;

    float4v Dacc[2][4];
#pragma unroll
    for (int ms = 0; ms < 2; ms++)
#pragma unroll
        for (int nt = 0; nt < 4; nt++) Dacc[ms][nt] = (float4v){0.f, 0.f, 0.f, 0.f};

    // stage batch 0
    {
        const char* qg = (const char*)(qb + (size_t)m0 * 64);
        const char* kg = (const char*)(kT + (size_t)n0 * 64);
#pragma unroll
        for (int kk = 0; kk < 4; kk++)
            dma16(qg + (w * 4 + kk) * 1024 + lane * 16, (char*)Sq[0] + (w * 4 + kk) * 1024);
        dma16(kg + (w * 2 + 0) * 1024 + lane * 16, (char*)Sk[0] + (w * 2 + 0) * 1024);
        dma16(kg + (w * 2 + 1) * 1024 + lane * 16, (char*)Sk[0] + (w * 2 + 1) * 1024);
    }

    for (int bb = 0; bb < BATCH; bb++) {
        const int p = bb & 1;
        if (bb < BATCH - 1) { // prefetch next batch into other buffer
            const char* qg = (const char*)(qb + (size_t)(bb + 1) * BSTRIDE + (size_t)m0 * 64);
            const char* kg = (const char*)(kT + (size_t)(bb + 1) * BSTRIDE + (size_t)n0 * 64);
#pragma unroll
            for (int kk = 0; kk < 4; kk++)
                dma16(qg + (w * 4 + kk) * 1024 + lane * 16, (char*)Sq[p ^ 1] + (w * 4 + kk) * 1024);
            dma16(kg + (w * 2 + 0) * 1024 + lane * 16, (char*)Sk[p ^ 1] + (w * 2 + 0) * 1024);
            dma16(kg + (w * 2 + 1) * 1024 + lane * 16, (char*)Sk[p ^ 1] + (w * 2 + 1) * 1024);
            asm volatile("s_waitcnt vmcnt(6)" ::: "memory"); // drain THIS batch, keep next in flight
        } else {
            asm volatile("s_waitcnt vmcnt(0)" ::: "memory");
        }
        asm volatile("s_barrier" ::: "memory");

        short8 Qf[2][2];
#pragma unroll
        for (int ms = 0; ms < 2; ms++)
#pragma unroll
            for (int h = 0; h < 2; h++)
                Qf[ms][h] = *(const short8*)&Sq[p][(w * 32 + ms * 16 + c) * 64 +
                                                  ((h * 4 + q) ^ (c & 7)) * 8];
#pragma unroll
        for (int nt = 0; nt < 4; nt++) {
            short8 A0 = *(const short8*)&Sk[p][(nt * 16 + c) * 64 + (q ^ (c & 7)) * 8];
            short8 A1 = *(const short8*)&Sk[p][(nt * 16 + c) * 64 + ((4 + q) ^ (c & 7)) * 8];
#pragma unroll
            for (int ms = 0; ms < 2; ms++) {
                float4v d = (float4v){0.f, 0.f, 0.f, 0.f};
                d = __builtin_amdgcn_mfma_f32_16x16x32_bf16(A0, Qf[ms][0], d, 0, 0, 0);
                d = __builtin_amdgcn_mfma_f32_16x16x32_bf16(A1, Qf[ms][1], d, 0, 0, 0);
#pragma unroll
                for (int r = 0; r < 4; r++) Dacc[ms][nt][r] += __expf(d[r]);
            }
        }
        asm volatile("s_barrier" ::: "memory"); // done reading buf p; next iter overwrites it
    }

    // Write frag-direct Dt: T = mt*64 + ng*2 + (nt>>1); slot (w, ms, nt&1, lane) as uint2.
#pragma unroll
    for (int ms = 0; ms < 2; ms++)
#pragma unroll
        for (int nt = 0; nt < 4; nt++) {
            unsigned int x = f2bf(1.f / Dacc[ms][nt][0]) |
                             ((unsigned)f2bf(1.f / Dacc[ms][nt][1]) << 16);
            unsigned int y = f2bf(1.f / Dacc[ms][nt][2]) |
                             ((unsigned)f2bf(1.f / Dacc[ms][nt][3]) << 16);
            size_t T = (size_t)(mt * 64 + ng * 2 + (nt >> 1));
            *(uint2*)((char*)Dt + T * 8192 + w * 2048 + (ms * 2 + (nt & 1)) * 512 + lane * 8) =
                make_uint2(x, y);
        }
}

// ---- Main: out_b += (exp(S_b)*Dinv) @ V_b. Grid 1024 = 16b x 16mt x 4ns; 4 blocks/CU.
// Double-buffered Sk/Sv staging with raw s_barrier + vmcnt(2): next step's DMAs stay
// in flight across the barrier. Dinv read frag-direct from global (coalesced dwordx2).
__global__ __launch_bounds__(256, 4) void attn_main_kernel(
    const unsigned short* __restrict__ qb, const unsigned short* __restrict__ kT,
    const unsigned short* __restrict__ vS, const unsigned short* __restrict__ Dt,
    float* __restrict__ out)
{
    __shared__ unsigned short Sk[2][2048];      // 2 x 4KB : 32n x 64i
    __shared__ unsigned short Sv[2][2048];      // 2 x 4KB : 64j x 32n
    __shared__ unsigned short Ep[4][2][16][40]; // 10KB wave-private P tiles

    const int tid = threadIdx.x, w = tid >> 6, lane = tid & 63;
    const int c = lane & 15, q = lane >> 4;
    const int b = blockIdx.x & 15, mt = (blockIdx.x >> 4) & 15, ns = blockIdx.x >> 8;
    const int m0 = mt * 128, nbase = ns * 512;

    const unsigned short* qb_b = qb + (size_t)b * BSTRIDE;
    const char* kbase = (const char*)(kT + (size_t)b * BSTRIDE);
    const char* vbase = (const char*)(vS + (size_t)b * BSTRIDE);

    short8 Qf[2][2];
#pragma unroll
    for (int ms = 0; ms < 2; ms++)
#pragma unroll
        for (int h = 0; h < 2; h++)
            Qf[ms][h] = *(const short8*)(qb_b + (m0 + w * 32 + ms * 16 + c) * 64 +
                                         ((h * 4 + q) ^ (c & 7)) * 8);
    float4v acc[2][4];
#pragma unroll
    for (int ms = 0; ms < 2; ms++)
#pragma unroll
        for (int jt = 0; jt < 4; jt++) acc[ms][jt] = (float4v){0.f, 0.f, 0.f, 0.f};

    // stage step 0
    dma16(kbase + (size_t)nbase * 128 + w * 1024 + lane * 16, (char*)Sk[0] + w * 1024);
    dma16(vbase + (size_t)(ns * 16) * 4096 + w * 1024 + lane * 16, (char*)Sv[0] + w * 1024);

    for (int st = 0; st < 16; st++) {
        const int p = st & 1;
        if (st < 15) { // prefetch next step into other buffer
            const int n1 = nbase + (st + 1) * 32;
            dma16(kbase + (size_t)n1 * 128 + w * 1024 + lane * 16, (char*)Sk[p ^ 1] + w * 1024);
            dma16(vbase + (size_t)(ns * 16 + st + 1) * 4096 + w * 1024 + lane * 16,
                  (char*)Sv[p ^ 1] + w * 1024);
            asm volatile("s_waitcnt vmcnt(2)" ::: "memory"); // drain this step, keep next in flight
        } else {
            asm volatile("s_waitcnt vmcnt(0)" ::: "memory");
        }
        asm volatile("s_barrier" ::: "memory");

        // Dinv frag-direct loads (coalesced 512B/wave per load)
        const char* dtb = (const char*)Dt + (size_t)(mt * 64 + ns * 16 + st) * 8192 +
                          w * 2048 + lane * 8;
        uint2 du[2][2];
        du[0][0] = *(const uint2*)(dtb + 0);
        du[0][1] = *(const uint2*)(dtb + 512);
        du[1][0] = *(const uint2*)(dtb + 1024);
        du[1][1] = *(const uint2*)(dtb + 1536);

        // GEMM1 (S^T) + exp*Dinv -> P bf16 into wave-private LDS
#pragma unroll
        for (int nt = 0; nt < 2; nt++) {
            short8 A0 = *(const short8*)&Sk[p][(nt * 16 + c) * 64 + (q ^ (c & 7)) * 8];
            short8 A1 = *(const short8*)&Sk[p][(nt * 16 + c) * 64 + ((4 + q) ^ (c & 7)) * 8];
#pragma unroll
            for (int ms = 0; ms < 2; ms++) {
                float4v d = (float4v){0.f, 0.f, 0.f, 0.f};
                d = __builtin_amdgcn_mfma_f32_16x16x32_bf16(A0, Qf[ms][0], d, 0, 0, 0);
                d = __builtin_amdgcn_mfma_f32_16x16x32_bf16(A1, Qf[ms][1], d, 0, 0, 0);
                uint2 u2 = du[ms][nt];
                ushort4 e;
                e.x = f2bf(__expf(d[0]) * __uint_as_float(u2.x << 16));
                e.y = f2bf(__expf(d[1]) * __uint_as_float(u2.x & 0xffff0000u));
                e.z = f2bf(__expf(d[2]) * __uint_as_float(u2.y << 16));
                e.w = f2bf(__expf(d[3]) * __uint_as_float(u2.y & 0xffff0000u));
                *(ushort4*)&Ep[w][ms][c][nt * 16 + q * 4] = e;
            }
        }
        asm volatile("s_waitcnt lgkmcnt(0)" ::: "memory"); // intra-wave P exchange

        // GEMM2: acc += P @ V
        short8 Vf[4];
#pragma unroll
        for (int jt = 0; jt < 4; jt++)
            Vf[jt] = *(const short8*)&Sv[p][(jt * 16 + c) * 32 + (q ^ (c & 3)) * 8];
#pragma unroll
        for (int ms = 0; ms < 2; ms++) {
            short8 Pf = *(const short8*)&Ep[w][ms][c][q * 8];
#pragma unroll
            for (int jt = 0; jt < 4; jt++)
                acc[ms][jt] = __builtin_amdgcn_mfma_f32_16x16x32_bf16(Pf, Vf[jt], acc[ms][jt], 0, 0, 0);
        }
        asm volatile("s_barrier" ::: "memory"); // all waves done reading buf p
    }

    // Epilogue: C/D col=c=j, row=q*4+r=m. 4 ns-blocks accumulate via atomics.
#pragma unroll
    for (int ms = 0; ms < 2; ms++)
#pragma unroll
        for (int jt = 0; jt < 4; jt++)
#pragma unroll
            for (int r = 0; r < 4; r++) {
                int m = m0 + w * 32 + ms * 16 + q * 4 + r;
                atomicAdd(&out[((size_t)b * CDIM + m) * LDIM + jt * 16 + c], acc[ms][jt][r]);
            }
}

extern "C" void kernel_launch(void* const* d_in, const int* in_sizes, int n_in,
                              void* d_out, int out_size, void* d_ws, size_t ws_size,
                              hipStream_t stream) {
    const float* q = (const float*)d_in[0];
    const float* k = (const float*)d_in[1];
    const float* v = (const float*)d_in[2];
    float* out = (float*)d_out;

    unsigned short* qb = (unsigned short*)d_ws;        // 4 MB bf16 swizzled (q*0.125)
    unsigned short* kT = qb + (size_t)BATCH * BSTRIDE; // 4 MB bf16 swizzled [b][n][i]
    unsigned short* vS = kT + (size_t)BATCH * BSTRIDE; // 4 MB bf16 tiled [b][nb][j][nn]
    unsigned short* Dt = vS + (size_t)BATCH * BSTRIDE; // 8 MB bf16 1/D frag-direct tiles

    prepass_kernel<<<3072, 256, 0, stream>>>(q, k, v, out, qb, kT, vS);
    dinv_kernel<<<512, 256, 0, stream>>>(qb, kT, Dt);
    attn_main_kernel<<<1024, 256, 0, stream>>>(qb, kT, vS, Dt, out);
}

// Round 6
// 129.636 us; speedup vs baseline: 1.0850x; 1.0850x over previous
//
#include <hip/hip_runtime.h>

typedef __attribute__((ext_vector_type(8))) short short8;
typedef __attribute__((ext_vector_type(4))) float float4v;

#define BATCH 16
#define CDIM 2048
#define LDIM 64
#define BSTRIDE (CDIM * LDIM) /* 131072 elems per batch */

__device__ __forceinline__ float bf2f(unsigned short u) {
    return __uint_as_float(((unsigned int)u) << 16);
}
__device__ __forceinline__ unsigned short f2bf(float f) {
    unsigned int x = __float_as_uint(f);
    x += 0x7fffu + ((x >> 16) & 1u); // RNE
    return (unsigned short)(x >> 16);
}
// Async global->LDS DMA: 16B/lane, lane i lands at lptr + i*16. lptr wave-uniform.
__device__ __forceinline__ void dma16(const void* g, void* l) {
    __builtin_amdgcn_global_load_lds(
        (const __attribute__((address_space(1))) void*)g,
        (__attribute__((address_space(3))) void*)l, 16, 0, 0);
}

// ---- Prepass (2048 blocks x 256):
//  [0,1024)    q*0.125 -> swizzled bf16 (chunk j at j^(m&7) within 128B row)
//  [1024,1536) k (64i x 2048n) -> kT[b][n][i] bf16, chunk-swizzled
//  [1536,2048) v (2048n x 64j) -> vS[b][nb][j][nn] bf16, chunk-swizzled
// (out is NOT zeroed: main writes it exactly once now.)
__global__ __launch_bounds__(256) void prepass_kernel(
    const float* __restrict__ q, const float* __restrict__ k, const float* __restrict__ v,
    unsigned short* __restrict__ qb,
    unsigned short* __restrict__ kT, unsigned short* __restrict__ vS)
{
    __shared__ unsigned short T[64][68];
    const int bx = blockIdx.x;
    const int t = threadIdx.x;

    if (bx < 1024) {
        int i = bx * 256 + t; // one 16B out-chunk (8 bf16) per thread
        const float4v* src = (const float4v*)q + (size_t)i * 2;
        float4v x0 = src[0], x1 = src[1];
        unsigned int u0 = f2bf(x0[0] * 0.125f) | ((unsigned)f2bf(x0[1] * 0.125f) << 16);
        unsigned int u1 = f2bf(x0[2] * 0.125f) | ((unsigned)f2bf(x0[3] * 0.125f) << 16);
        unsigned int u2 = f2bf(x1[0] * 0.125f) | ((unsigned)f2bf(x1[1] * 0.125f) << 16);
        unsigned int u3 = f2bf(x1[2] * 0.125f) | ((unsigned)f2bf(x1[3] * 0.125f) << 16);
        int b = i >> 14, r = i & 16383, m = r >> 3, j = r & 7;
        *(uint4*)(qb + (size_t)b * BSTRIDE + m * 64 + (j ^ (m & 7)) * 8) =
            make_uint4(u0, u1, u2, u3);
    } else if (bx < 1536) { // k-transpose: tile = all 64 i x 64 n
        int idx = bx - 1024, b = idx >> 5, n0 = (idx & 31) * 64;
        const float* src = k + (size_t)b * BSTRIDE + (size_t)(t >> 2) * 2048 + n0 + (t & 3) * 16;
#pragma unroll
        for (int kk = 0; kk < 4; kk++) {
            float4v x = *(const float4v*)(src + kk * 4);
#pragma unroll
            for (int e = 0; e < 4; e++)
                T[t >> 2][(t & 3) * 16 + kk * 4 + e] = f2bf(x[e]);
        }
        __syncthreads();
        unsigned short* dst = kT + (size_t)b * BSTRIDE;
        int n = t & 63;
#pragma unroll
        for (int jj = 0; jj < 2; jj++) {
            int j = (t >> 6) * 2 + jj;
            ushort4 g0, g1;
#pragma unroll
            for (int e = 0; e < 4; e++) { g0[e] = T[j * 8 + e][n]; g1[e] = T[j * 8 + 4 + e][n]; }
            *(uint4*)(dst + (size_t)(n0 + n) * 64 + (j ^ (n & 7)) * 8) =
                make_uint4(g0.x | ((unsigned)g0.y << 16), g0.z | ((unsigned)g0.w << 16),
                           g1.x | ((unsigned)g1.y << 16), g1.z | ((unsigned)g1.w << 16));
        }
    } else { // v-transpose: tile = 64 n x 64 j
        int idx = bx - 1536, b = idx >> 5, n0 = (idx & 31) * 64;
        const float* src = v + (size_t)b * BSTRIDE + (size_t)n0 * 64 +
                           (size_t)(t >> 2) * 64 + (t & 3) * 16;
#pragma unroll
        for (int kk = 0; kk < 4; kk++) {
            float4v x = *(const float4v*)(src + kk * 4);
#pragma unroll
            for (int e = 0; e < 4; e++)
                T[t >> 2][(t & 3) * 16 + kk * 4 + e] = f2bf(x[e]); // T[n][j]
        }
        __syncthreads();
        unsigned short* dst = vS + (size_t)b * BSTRIDE;
        int j = t & 63, qc = t >> 6;
#pragma unroll
        for (int nb = 0; nb < 2; nb++) {
            ushort4 g0, g1;
#pragma unroll
            for (int e = 0; e < 4; e++) {
                g0[e] = T[nb * 32 + qc * 8 + e][j];
                g1[e] = T[nb * 32 + qc * 8 + 4 + e][j];
            }
            *(uint4*)(dst + (size_t)(n0 / 32 + nb) * 2048 + j * 32 + (qc ^ (j & 3)) * 8) =
                make_uint4(g0.x | ((unsigned)g0.y << 16), g0.z | ((unsigned)g0.w << 16),
                           g1.x | ((unsigned)g1.y << 16), g1.z | ((unsigned)g1.w << 16));
        }
    }
}

// ---- dinv: frag-direct Dt[T][g][ms][nt][lane] (uint2 of 4 bf16 1/D). Pipelined over batches.
__global__ __launch_bounds__(256, 2) void dinv_kernel(
    const unsigned short* __restrict__ qb, const unsigned short* __restrict__ kT,
    unsigned short* __restrict__ Dt)
{
    __shared__ unsigned short Sq[2][8192]; // 2 x 16KB : 128m x 64i
    __shared__ unsigned short Sk[2][4096]; // 2 x 8KB  : 64n x 64i
    const int tid = threadIdx.x, w = tid >> 6, lane = tid & 63;
    const int c = lane & 15, q = lane >> 4;
    const int mt = blockIdx.x & 15, ng = blockIdx.x >> 4;
    const int m0 = mt * 128, n0 = ng * 64;

    float4v Dacc[2][4];
#pragma unroll
    for (int ms = 0; ms < 2; ms++)
#pragma unroll
        for (int nt = 0; nt < 4; nt++) Dacc[ms][nt] = (float4v){0.f, 0.f, 0.f, 0.f};

    {
        const char* qg = (const char*)(qb + (size_t)m0 * 64);
        const char* kg = (const char*)(kT + (size_t)n0 * 64);
#pragma unroll
        for (int kk = 0; kk < 4; kk++)
            dma16(qg + (w * 4 + kk) * 1024 + lane * 16, (char*)Sq[0] + (w * 4 + kk) * 1024);
        dma16(kg + (w * 2 + 0) * 1024 + lane * 16, (char*)Sk[0] + (w * 2 + 0) * 1024);
        dma16(kg + (w * 2 + 1) * 1024 + lane * 16, (char*)Sk[0] + (w * 2 + 1) * 1024);
    }

    for (int bb = 0; bb < BATCH; bb++) {
        const int p = bb & 1;
        if (bb < BATCH - 1) {
            const char* qg = (const char*)(qb + (size_t)(bb + 1) * BSTRIDE + (size_t)m0 * 64);
            const char* kg = (const char*)(kT + (size_t)(bb + 1) * BSTRIDE + (size_t)n0 * 64);
#pragma unroll
            for (int kk = 0; kk < 4; kk++)
                dma16(qg + (w * 4 + kk) * 1024 + lane * 16, (char*)Sq[p ^ 1] + (w * 4 + kk) * 1024);
            dma16(kg + (w * 2 + 0) * 1024 + lane * 16, (char*)Sk[p ^ 1] + (w * 2 + 0) * 1024);
            dma16(kg + (w * 2 + 1) * 1024 + lane * 16, (char*)Sk[p ^ 1] + (w * 2 + 1) * 1024);
            asm volatile("s_waitcnt vmcnt(6)" ::: "memory");
        } else {
            asm volatile("s_waitcnt vmcnt(0)" ::: "memory");
        }
        asm volatile("s_barrier" ::: "memory");

        short8 Qf[2][2];
#pragma unroll
        for (int ms = 0; ms < 2; ms++)
#pragma unroll
            for (int h = 0; h < 2; h++)
                Qf[ms][h] = *(const short8*)&Sq[p][(w * 32 + ms * 16 + c) * 64 +
                                                  ((h * 4 + q) ^ (c & 7)) * 8];
#pragma unroll
        for (int nt = 0; nt < 4; nt++) {
            short8 A0 = *(const short8*)&Sk[p][(nt * 16 + c) * 64 + (q ^ (c & 7)) * 8];
            short8 A1 = *(const short8*)&Sk[p][(nt * 16 + c) * 64 + ((4 + q) ^ (c & 7)) * 8];
#pragma unroll
            for (int ms = 0; ms < 2; ms++) {
                float4v d = (float4v){0.f, 0.f, 0.f, 0.f};
                d = __builtin_amdgcn_mfma_f32_16x16x32_bf16(A0, Qf[ms][0], d, 0, 0, 0);
                d = __builtin_amdgcn_mfma_f32_16x16x32_bf16(A1, Qf[ms][1], d, 0, 0, 0);
#pragma unroll
                for (int r = 0; r < 4; r++) Dacc[ms][nt][r] += __expf(d[r]);
            }
        }
        asm volatile("s_barrier" ::: "memory");
    }

#pragma unroll
    for (int ms = 0; ms < 2; ms++)
#pragma unroll
        for (int nt = 0; nt < 4; nt++) {
            unsigned int x = f2bf(1.f / Dacc[ms][nt][0]) |
                             ((unsigned)f2bf(1.f / Dacc[ms][nt][1]) << 16);
            unsigned int y = f2bf(1.f / Dacc[ms][nt][2]) |
                             ((unsigned)f2bf(1.f / Dacc[ms][nt][3]) << 16);
            size_t T = (size_t)(mt * 64 + ng * 2 + (nt >> 1));
            *(uint2*)((char*)Dt + T * 8192 + w * 2048 + (ms * 2 + (nt & 1)) * 512 + lane * 8) =
                make_uint2(x, y);
        }
}

// ---- Main: out_b = (exp(S_b)*Dinv) @ V_b. Grid 256 = 16b x 16mt; block 1024 = 16 waves.
// wave w: g = w>>2 (m-sub of 32 within 128), ns = w&3 (n-split of 512). 16 steps of 32n.
// Double-buffered Sk/Sv per ns-group (DMA split across the 4 g-waves), vmcnt(2) pipelining.
// NO atomics: 4-round LDS reduction across ns, then coalesced float4 stores.
__global__ __launch_bounds__(1024, 4) void attn_main_kernel(
    const unsigned short* __restrict__ qb, const unsigned short* __restrict__ kT,
    const unsigned short* __restrict__ vS, const unsigned short* __restrict__ Dt,
    float* __restrict__ out)
{
    __shared__ unsigned short Sk[4][2][2048];   // per-ns double-buf: 32n x 64i  (32 KB)
    __shared__ unsigned short Sv[4][2][2048];   // per-ns double-buf: 64j x 32n  (32 KB)
    __shared__ unsigned short Ep[16][2][16][40]; // wave-private P tiles          (40 KB)

    const int tid = threadIdx.x, w = tid >> 6, lane = tid & 63;
    const int c = lane & 15, q = lane >> 4;
    const int g = w >> 2, ns = w & 3;
    const int b = blockIdx.x & 15, mt = blockIdx.x >> 4;
    const int m0 = mt * 128 + g * 32;
    const int nbase = ns * 512;

    const unsigned short* qb_b = qb + (size_t)b * BSTRIDE;
    const char* kbase = (const char*)(kT + (size_t)b * BSTRIDE);
    const char* vbase = (const char*)(vS + (size_t)b * BSTRIDE);

    short8 Qf[2][2];
#pragma unroll
    for (int ms = 0; ms < 2; ms++)
#pragma unroll
        for (int h = 0; h < 2; h++)
            Qf[ms][h] = *(const short8*)(qb_b + (m0 + ms * 16 + c) * 64 +
                                         ((h * 4 + q) ^ (c & 7)) * 8);
    float4v acc[2][4];
#pragma unroll
    for (int ms = 0; ms < 2; ms++)
#pragma unroll
        for (int jt = 0; jt < 4; jt++) acc[ms][jt] = (float4v){0.f, 0.f, 0.f, 0.f};

    // stage step 0: wave g of each ns-group loads chunk g of Sk[ns] and Sv[ns]
    dma16(kbase + (size_t)nbase * 128 + g * 1024 + lane * 16, (char*)Sk[ns][0] + g * 1024);
    dma16(vbase + (size_t)(ns * 16) * 4096 + g * 1024 + lane * 16, (char*)Sv[ns][0] + g * 1024);

    for (int st = 0; st < 16; st++) {
        const int p = st & 1;
        if (st < 15) {
            const int n1 = nbase + (st + 1) * 32;
            dma16(kbase + (size_t)n1 * 128 + g * 1024 + lane * 16, (char*)Sk[ns][p ^ 1] + g * 1024);
            dma16(vbase + (size_t)(ns * 16 + st + 1) * 4096 + g * 1024 + lane * 16,
                  (char*)Sv[ns][p ^ 1] + g * 1024);
            asm volatile("s_waitcnt vmcnt(2)" ::: "memory");
        } else {
            asm volatile("s_waitcnt vmcnt(0)" ::: "memory");
        }
        asm volatile("s_barrier" ::: "memory");

        // Dinv frag-direct loads (coalesced 512B/wave per load)
        const char* dtb = (const char*)Dt + (size_t)(mt * 64 + ns * 16 + st) * 8192 +
                          g * 2048 + lane * 8;
        uint2 du[2][2];
        du[0][0] = *(const uint2*)(dtb + 0);
        du[0][1] = *(const uint2*)(dtb + 512);
        du[1][0] = *(const uint2*)(dtb + 1024);
        du[1][1] = *(const uint2*)(dtb + 1536);

        // GEMM1 (S^T) + exp*Dinv -> P bf16 into wave-private LDS
#pragma unroll
        for (int nt = 0; nt < 2; nt++) {
            short8 A0 = *(const short8*)&Sk[ns][p][(nt * 16 + c) * 64 + (q ^ (c & 7)) * 8];
            short8 A1 = *(const short8*)&Sk[ns][p][(nt * 16 + c) * 64 + ((4 + q) ^ (c & 7)) * 8];
#pragma unroll
            for (int ms = 0; ms < 2; ms++) {
                float4v d = (float4v){0.f, 0.f, 0.f, 0.f};
                d = __builtin_amdgcn_mfma_f32_16x16x32_bf16(A0, Qf[ms][0], d, 0, 0, 0);
                d = __builtin_amdgcn_mfma_f32_16x16x32_bf16(A1, Qf[ms][1], d, 0, 0, 0);
                uint2 u2 = du[ms][nt];
                ushort4 e;
                e.x = f2bf(__expf(d[0]) * __uint_as_float(u2.x << 16));
                e.y = f2bf(__expf(d[1]) * __uint_as_float(u2.x & 0xffff0000u));
                e.z = f2bf(__expf(d[2]) * __uint_as_float(u2.y << 16));
                e.w = f2bf(__expf(d[3]) * __uint_as_float(u2.y & 0xffff0000u));
                *(ushort4*)&Ep[w][ms][c][nt * 16 + q * 4] = e;
            }
        }
        asm volatile("s_waitcnt lgkmcnt(0)" ::: "memory"); // intra-wave P exchange

        // GEMM2: acc += P @ V
        short8 Vf[4];
#pragma unroll
        for (int jt = 0; jt < 4; jt++)
            Vf[jt] = *(const short8*)&Sv[ns][p][(jt * 16 + c) * 32 + (q ^ (c & 3)) * 8];
#pragma unroll
        for (int ms = 0; ms < 2; ms++) {
            short8 Pf = *(const short8*)&Ep[w][ms][c][q * 8];
#pragma unroll
            for (int jt = 0; jt < 4; jt++)
                acc[ms][jt] = __builtin_amdgcn_mfma_f32_16x16x32_bf16(Pf, Vf[jt], acc[ms][jt], 0, 0, 0);
        }
        asm volatile("s_barrier" ::: "memory");
    }

    // ---- Epilogue: reduce across ns via LDS (alias staging region), no atomics ----
    float* Racc = (float*)&Sk[0][0][0]; // 4 regions of 32 rows x pitch 68 fp32 (34.8 KB)
    float* Rg = Racc + g * 2176;
    __syncthreads(); // all staging reads done; safe to overwrite
#pragma unroll 1
    for (int round = 0; round < 4; round++) {
        if (ns == round) {
#pragma unroll
            for (int ms = 0; ms < 2; ms++)
#pragma unroll
                for (int jt = 0; jt < 4; jt++)
#pragma unroll
                    for (int r = 0; r < 4; r++) {
                        int idx = (ms * 16 + q * 4 + r) * 68 + jt * 16 + c;
                        if (round == 0) Rg[idx] = acc[ms][jt][r];
                        else Rg[idx] += acc[ms][jt][r];
                    }
        }
        __syncthreads();
    }
    // Coalesced store: thread t -> row mrow = t>>3 (of 128), cols (t&7)*8 .. +7
    {
        int mrow = tid >> 3, col0 = (tid & 7) * 8;
        const float* src = Racc + (mrow >> 5) * 2176 + (mrow & 31) * 68 + col0;
        float4v v0 = *(const float4v*)(src);
        float4v v1 = *(const float4v*)(src + 4);
        float* dst = out + ((size_t)b * CDIM + mt * 128 + mrow) * LDIM + col0;
        *(float4v*)(dst) = v0;
        *(float4v*)(dst + 4) = v1;
    }
}

extern "C" void kernel_launch(void* const* d_in, const int* in_sizes, int n_in,
                              void* d_out, int out_size, void* d_ws, size_t ws_size,
                              hipStream_t stream) {
    const float* q = (const float*)d_in[0];
    const float* k = (const float*)d_in[1];
    const float* v = (const float*)d_in[2];
    float* out = (float*)d_out;

    unsigned short* qb = (unsigned short*)d_ws;        // 4 MB bf16 swizzled (q*0.125)
    unsigned short* kT = qb + (size_t)BATCH * BSTRIDE; // 4 MB bf16 swizzled [b][n][i]
    unsigned short* vS = kT + (size_t)BATCH * BSTRIDE; // 4 MB bf16 tiled [b][nb][j][nn]
    unsigned short* Dt = vS + (size_t)BATCH * BSTRIDE; // 8 MB bf16 1/D frag-direct tiles

    prepass_kernel<<<2048, 256, 0, stream>>>(q, k, v, qb, kT, vS);
    dinv_kernel<<<512, 256, 0, stream>>>(qb, kT, Dt);
    attn_main_kernel<<<256, 1024, 0, stream>>>(qb, kT, vS, Dt, out);
}